// Round 1
// baseline (2204.804 us; speedup 1.0000x reference)
//
#include <hip/hip_runtime.h>
#include <hip/hip_bf16.h>
#include <math.h>

#define SEQ_LEN 3120
#define DIM 1536
#define QKV_N 4608
#define HEADS 12
#define HEAD_DIM 128
#define FRAME_LEN 1560

// ---------------------------------------------------------------------------
// Generic tiled fp32 GEMM with bias: C[M,N] = A[M,K] @ B[K,N] + bias[N]
// 128x128 tile, BK=16, 256 threads, 8x8 register block per thread.
// ---------------------------------------------------------------------------
#define GM_TM 128
#define GM_TN 128
#define GM_TK 16

__global__ __launch_bounds__(256, 2) void gemm_bias_kernel(
    const float* __restrict__ A, const float* __restrict__ B,
    const float* __restrict__ bias, float* __restrict__ C,
    int M, int N, int K)
{
    __shared__ __align__(16) float As[GM_TK][GM_TM + 4]; // k-major (transposed)
    __shared__ __align__(16) float Bs[GM_TK][GM_TN + 4];

    const int tid = threadIdx.x;
    const int tx = tid & 15;   // output col group (8 cols)
    const int ty = tid >> 4;   // output row group (8 rows)
    const int m0 = blockIdx.y * GM_TM;
    const int n0 = blockIdx.x * GM_TN;

    // A-load mapping: 2 threads per row, 8 floats each
    const int ar = tid >> 1;
    const int ac = (tid & 1) * 8;
    // B-load mapping: 16 threads per row, 8 floats each
    const int br = tid >> 4;
    const int bc = (tid & 15) * 8;

    float acc[8][8];
#pragma unroll
    for (int i = 0; i < 8; ++i)
#pragma unroll
        for (int j = 0; j < 8; ++j) acc[i][j] = 0.f;

    for (int k0 = 0; k0 < K; k0 += GM_TK) {
        // stage A tile (transposed into As[k][m])
        {
            const int gm = m0 + ar;
            float4 v0 = make_float4(0.f, 0.f, 0.f, 0.f), v1 = v0;
            if (gm < M) {
                const float* ap = A + (size_t)gm * K + k0 + ac;
                v0 = *(const float4*)(ap);
                v1 = *(const float4*)(ap + 4);
            }
            As[ac + 0][ar] = v0.x; As[ac + 1][ar] = v0.y;
            As[ac + 2][ar] = v0.z; As[ac + 3][ar] = v0.w;
            As[ac + 4][ar] = v1.x; As[ac + 5][ar] = v1.y;
            As[ac + 6][ar] = v1.z; As[ac + 7][ar] = v1.w;
        }
        // stage B tile
        {
            const float* bp = B + (size_t)(k0 + br) * N + n0 + bc;
            float4 v0 = *(const float4*)(bp);
            float4 v1 = *(const float4*)(bp + 4);
            *(float4*)&Bs[br][bc] = v0;
            *(float4*)&Bs[br][bc + 4] = v1;
        }
        __syncthreads();

#pragma unroll
        for (int kk = 0; kk < GM_TK; ++kk) {
            float4 a0 = *(const float4*)&As[kk][ty * 8];
            float4 a1 = *(const float4*)&As[kk][ty * 8 + 4];
            float4 b0 = *(const float4*)&Bs[kk][tx * 8];
            float4 b1 = *(const float4*)&Bs[kk][tx * 8 + 4];
            float av[8] = {a0.x, a0.y, a0.z, a0.w, a1.x, a1.y, a1.z, a1.w};
            float bv[8] = {b0.x, b0.y, b0.z, b0.w, b1.x, b1.y, b1.z, b1.w};
#pragma unroll
            for (int i = 0; i < 8; ++i)
#pragma unroll
                for (int j = 0; j < 8; ++j)
                    acc[i][j] = fmaf(av[i], bv[j], acc[i][j]);
        }
        __syncthreads();
    }

#pragma unroll
    for (int i = 0; i < 8; ++i) {
        const int gm = m0 + ty * 8 + i;
        if (gm < M) {
            float* cp = C + (size_t)gm * N + n0 + tx * 8;
#pragma unroll
            for (int j = 0; j < 8; ++j)
                cp[j] = acc[i][j] + bias[n0 + tx * 8 + j];
        }
    }
}

// ---------------------------------------------------------------------------
// Fused RMSNorm (over full DIM for q and k separately) + RoPE, in-place on the
// qkv buffer. One block per sequence position; 256 threads; 3 pairs each.
// ---------------------------------------------------------------------------
__global__ __launch_bounds__(256) void rmsrope_kernel(
    float* __restrict__ qkv, const float* __restrict__ gq,
    const float* __restrict__ gk, const float* __restrict__ cosf,
    const float* __restrict__ sinf)
{
    const int s = blockIdx.x;
    const int tid = threadIdx.x;
    float* qrow = qkv + (size_t)s * QKV_N;
    float* krow = qrow + DIM;

    float2 qp[3], kp[3];
    float ssq_q = 0.f, ssq_k = 0.f;
#pragma unroll
    for (int j = 0; j < 3; ++j) {
        const int p = tid + j * 256;
        qp[j] = *(const float2*)(qrow + 2 * p);
        kp[j] = *(const float2*)(krow + 2 * p);
        ssq_q += qp[j].x * qp[j].x + qp[j].y * qp[j].y;
        ssq_k += kp[j].x * kp[j].x + kp[j].y * kp[j].y;
    }
    // wave + block reduction
#pragma unroll
    for (int off = 32; off > 0; off >>= 1) {
        ssq_q += __shfl_down(ssq_q, off);
        ssq_k += __shfl_down(ssq_k, off);
    }
    __shared__ float wq[4], wk[4];
    const int wave = tid >> 6, lane = tid & 63;
    if (lane == 0) { wq[wave] = ssq_q; wk[wave] = ssq_k; }
    __syncthreads();
    const float tq = wq[0] + wq[1] + wq[2] + wq[3];
    const float tk = wk[0] + wk[1] + wk[2] + wk[3];
    const float inv_q = rsqrtf(tq * (1.0f / DIM) + 1e-6f);
    const float inv_k = rsqrtf(tk * (1.0f / DIM) + 1e-6f);

#pragma unroll
    for (int j = 0; j < 3; ++j) {
        const int p = tid + j * 256;
        const int fi = p & 63; // pair index within head
        const float c = cosf[s * 64 + fi];
        const float si = sinf[s * 64 + fi];
        {
            const float y1 = qp[j].x * inv_q * gq[2 * p];
            const float y2 = qp[j].y * inv_q * gq[2 * p + 1];
            *(float2*)(qrow + 2 * p) = make_float2(y1 * c - y2 * si, y1 * si + y2 * c);
        }
        {
            const float y1 = kp[j].x * inv_k * gk[2 * p];
            const float y2 = kp[j].y * inv_k * gk[2 * p + 1];
            *(float2*)(krow + 2 * p) = make_float2(y1 * c - y2 * si, y1 * si + y2 * c);
        }
    }
}

// ---------------------------------------------------------------------------
// Flash-style block-causal attention, fp32 vector math.
// Grid: (num_q_tiles, heads). BQ=64, BK=32, HD=128. Q and K staged transposed
// in LDS for vectorized fragment reads; K/V share one LDS buffer (aliased).
// ---------------------------------------------------------------------------
#define AT_BQ 64
#define AT_BK 32
#define KT_STRIDE 34   // Kt[d][j], padded
#define PT_STRIDE 68   // Pt[kk][i], padded (mult of 4 for float4)

__global__ __launch_bounds__(256, 2) void attn_kernel(
    const float* __restrict__ qkv, float* __restrict__ out)
{
    __shared__ __align__(16) float Qt[HEAD_DIM][AT_BQ];        // 32768 B
    __shared__ __align__(16) float KVs[HEAD_DIM * KT_STRIDE];  // 17408 B (union K^T / V)
    __shared__ __align__(16) float Pt[AT_BK][PT_STRIDE];       // 8704 B
    __shared__ float red[AT_BQ][17];                            // 4352 B
    __shared__ float rowm[AT_BQ], rowl[AT_BQ], rowa[AT_BQ];     // 768 B

    const int tid = threadIdx.x;
    const int head = blockIdx.y;
    const int q0 = blockIdx.x * AT_BQ;
    const float scale = 0.08838834764831845f; // 1/sqrt(128)

    // ---- load Q tile, scaled, transposed: Qt[d][r] ----
    {
        const int r = tid >> 2;             // 0..63
        const int dbase = (tid & 3) * 32;   // 4 threads/row, 32 floats each
        const int gs = q0 + r;
        const float* qp = qkv + (size_t)gs * QKV_N + head * HEAD_DIM + dbase;
#pragma unroll
        for (int v = 0; v < 8; ++v) {
            float4 x = make_float4(0.f, 0.f, 0.f, 0.f);
            if (gs < SEQ_LEN) x = *(const float4*)(qp + v * 4);
            const int d = dbase + v * 4;
            Qt[d + 0][r] = x.x * scale;
            Qt[d + 1][r] = x.y * scale;
            Qt[d + 2][r] = x.z * scale;
            Qt[d + 3][r] = x.w * scale;
        }
    }
    if (tid < AT_BQ) { rowm[tid] = -3.0e38f; rowl[tid] = 0.f; }

    const int i0 = (tid >> 4) * 4;  // 4 query rows owned in S and PV phases
    const int j0 = (tid & 15) * 2;  // 2 key cols in S phase
    const int dg = tid & 15;        // 8 d-cols group in PV phase

    float o[4][8];
#pragma unroll
    for (int ii = 0; ii < 4; ++ii)
#pragma unroll
        for (int dd = 0; dd < 8; ++dd) o[ii][dd] = 0.f;

    const int lastrow = min(q0 + AT_BQ - 1, SEQ_LEN - 1);
    const int Lmax = (lastrow < FRAME_LEN) ? FRAME_LEN : SEQ_LEN;

    for (int kc = 0; kc < Lmax; kc += AT_BK) {
        const int kvalid = min(AT_BK, Lmax - kc);

        // ---- stage K chunk transposed: Kt[d][j] ----
        {
            const int j = tid >> 3;
            const int dbase = (tid & 7) * 16;
            const float* kp = qkv + (size_t)(kc + j) * QKV_N + DIM + head * HEAD_DIM + dbase;
            const bool val = (j < kvalid);
#pragma unroll
            for (int v = 0; v < 4; ++v) {
                float4 x = make_float4(0.f, 0.f, 0.f, 0.f);
                if (val) x = *(const float4*)(kp + v * 4);
                const int d = dbase + v * 4;
                KVs[(d + 0) * KT_STRIDE + j] = x.x;
                KVs[(d + 1) * KT_STRIDE + j] = x.y;
                KVs[(d + 2) * KT_STRIDE + j] = x.z;
                KVs[(d + 3) * KT_STRIDE + j] = x.w;
            }
        }
        __syncthreads();

        // ---- S = (Q*scale) @ K^T : 4x2 per thread ----
        float sc[4][2] = {{0.f, 0.f}, {0.f, 0.f}, {0.f, 0.f}, {0.f, 0.f}};
#pragma unroll 8
        for (int kk = 0; kk < HEAD_DIM; ++kk) {
            float4 a = *(const float4*)&Qt[kk][i0];
            float2 b = *(const float2*)&KVs[kk * KT_STRIDE + j0];
            sc[0][0] = fmaf(a.x, b.x, sc[0][0]); sc[0][1] = fmaf(a.x, b.y, sc[0][1]);
            sc[1][0] = fmaf(a.y, b.x, sc[1][0]); sc[1][1] = fmaf(a.y, b.y, sc[1][1]);
            sc[2][0] = fmaf(a.z, b.x, sc[2][0]); sc[2][1] = fmaf(a.z, b.y, sc[2][1]);
            sc[3][0] = fmaf(a.w, b.x, sc[3][0]); sc[3][1] = fmaf(a.w, b.y, sc[3][1]);
        }

        // ---- block-causal mask + tail mask ----
#pragma unroll
        for (int ii = 0; ii < 4; ++ii) {
            const int sg = q0 + i0 + ii;
            const int Li = (sg < FRAME_LEN) ? FRAME_LEN : SEQ_LEN;
#pragma unroll
            for (int jj = 0; jj < 2; ++jj) {
                const int kg = kc + j0 + jj;
                if (kg >= Li || (j0 + jj) >= kvalid) sc[ii][jj] = -3.0e38f;
            }
        }

        // ---- online softmax: row max ----
#pragma unroll
        for (int ii = 0; ii < 4; ++ii)
            red[i0 + ii][tid & 15] = fmaxf(sc[ii][0], sc[ii][1]);
        __syncthreads();
        if (tid < AT_BQ) {
            float m = rowm[tid];
            const float mold = m;
#pragma unroll
            for (int j = 0; j < 16; ++j) m = fmaxf(m, red[tid][j]);
            rowm[tid] = m;
            rowa[tid] = __expf(mold - m);
        }
        __syncthreads();

        // ---- P = exp(S - m), write transposed Pt[j][i], partial row sums ----
#pragma unroll
        for (int ii = 0; ii < 4; ++ii) {
            const float m = rowm[i0 + ii];
            const float p0 = __expf(sc[ii][0] - m);
            const float p1 = __expf(sc[ii][1] - m);
            Pt[j0][i0 + ii] = p0;
            Pt[j0 + 1][i0 + ii] = p1;
            red[i0 + ii][tid & 15] = p0 + p1;
        }
        __syncthreads();
        if (tid < AT_BQ) {
            float ssum = 0.f;
#pragma unroll
            for (int j = 0; j < 16; ++j) ssum += red[tid][j];
            rowl[tid] = rowl[tid] * rowa[tid] + ssum;
        }

        // ---- stage V chunk (plain layout [j][d]) into the aliased buffer ----
        {
            const int j = tid >> 3;
            const int dbase = (tid & 7) * 16;
            const float* vp = qkv + (size_t)(kc + j) * QKV_N + 2 * DIM + head * HEAD_DIM + dbase;
            const bool val = (j < kvalid);
#pragma unroll
            for (int v = 0; v < 4; ++v) {
                float4 x = make_float4(0.f, 0.f, 0.f, 0.f);
                if (val) x = *(const float4*)(vp + v * 4);
                *(float4*)&KVs[j * HEAD_DIM + dbase + v * 4] = x;
            }
        }
        __syncthreads();

        // ---- rescale O, accumulate O += P @ V : 4 rows x 8 d-cols ----
#pragma unroll
        for (int ii = 0; ii < 4; ++ii) {
            const float a = rowa[i0 + ii];
#pragma unroll
            for (int dd = 0; dd < 8; ++dd) o[ii][dd] *= a;
        }
#pragma unroll 8
        for (int kk = 0; kk < AT_BK; ++kk) {
            float4 p = *(const float4*)&Pt[kk][i0];
            float4 v0 = *(const float4*)&KVs[kk * HEAD_DIM + dg * 8];
            float4 v1 = *(const float4*)&KVs[kk * HEAD_DIM + dg * 8 + 4];
            const float pv[4] = {p.x, p.y, p.z, p.w};
            const float vv[8] = {v0.x, v0.y, v0.z, v0.w, v1.x, v1.y, v1.z, v1.w};
#pragma unroll
            for (int ii = 0; ii < 4; ++ii)
#pragma unroll
                for (int dd = 0; dd < 8; ++dd)
                    o[ii][dd] = fmaf(pv[ii], vv[dd], o[ii][dd]);
        }
        __syncthreads(); // protect Kt/Vs/Pt/red for next chunk
    }

    // ---- epilogue: O /= l, store [s][head*128 + d] ----
#pragma unroll
    for (int ii = 0; ii < 4; ++ii) {
        const int sg = q0 + i0 + ii;
        if (sg < SEQ_LEN) {
            const float invl = 1.0f / rowl[i0 + ii];
            float* op = out + (size_t)sg * DIM + head * HEAD_DIM + dg * 8;
            float4 r0 = make_float4(o[ii][0] * invl, o[ii][1] * invl,
                                    o[ii][2] * invl, o[ii][3] * invl);
            float4 r1 = make_float4(o[ii][4] * invl, o[ii][5] * invl,
                                    o[ii][6] * invl, o[ii][7] * invl);
            *(float4*)op = r0;
            *(float4*)(op + 4) = r1;
        }
    }
}

// ---------------------------------------------------------------------------
extern "C" void kernel_launch(void* const* d_in, const int* in_sizes, int n_in,
                              void* d_out, int out_size, void* d_ws, size_t ws_size,
                              hipStream_t stream)
{
    const float* hs    = (const float*)d_in[0]; // (1, 3120, 1536)
    const float* cosf  = (const float*)d_in[1]; // (3120, 64)
    const float* sinf  = (const float*)d_in[2]; // (3120, 64)
    const float* w_qkv = (const float*)d_in[3]; // (1536, 4608)
    const float* b_qkv = (const float*)d_in[4]; // (4608,)
    const float* g_q   = (const float*)d_in[5]; // (1536,)
    const float* g_k   = (const float*)d_in[6]; // (1536,)
    const float* w_out = (const float*)d_in[7]; // (1536, 1536)
    const float* b_out = (const float*)d_in[8]; // (1536,)
    // d_in[9] = frame_len (1560), compile-time constant here

    float* qkv  = (float*)d_ws;                         // 3120*4608 fp32 = 57.5 MB
    float* attn = qkv + (size_t)SEQ_LEN * QKV_N;        // 3120*1536 fp32 = 19.2 MB
    float* outp = (float*)d_out;

    // 1) qkv = hs @ w_qkv + b_qkv
    gemm_bias_kernel<<<dim3(QKV_N / GM_TN, (SEQ_LEN + GM_TM - 1) / GM_TM), 256, 0, stream>>>(
        hs, w_qkv, b_qkv, qkv, SEQ_LEN, QKV_N, DIM);

    // 2) rmsnorm(q,k) + rope(q,k), in place
    rmsrope_kernel<<<SEQ_LEN, 256, 0, stream>>>(qkv, g_q, g_k, cosf, sinf);

    // 3) block-causal flash attention -> attn [3120, 1536]
    attn_kernel<<<dim3((SEQ_LEN + AT_BQ - 1) / AT_BQ, HEADS), 256, 0, stream>>>(qkv, attn);

    // 4) out = attn @ w_out + b_out
    gemm_bias_kernel<<<dim3(DIM / GM_TN, (SEQ_LEN + GM_TM - 1) / GM_TM), 256, 0, stream>>>(
        attn, w_out, b_out, outp, SEQ_LEN, DIM, DIM);
}

// Round 2
// 558.248 us; speedup vs baseline: 3.9495x; 3.9495x over previous
//
#include <hip/hip_runtime.h>
#include <stdint.h>

#define SEQ_LEN 3120
#define DIM 1536
#define QKV_N 4608
#define HEADS 12
#define HEAD_DIM 128
#define FRAME_LEN 1560
#define SM_SCALE 0.08838834764831845f // 1/sqrt(128)

typedef short short8 __attribute__((ext_vector_type(8)));
typedef float f32x4 __attribute__((ext_vector_type(4)));

// fp32 -> bf16 round-to-nearest-even (data has no NaN)
__device__ __forceinline__ unsigned short f2bf(float x) {
    union { float f; unsigned u; } v; v.f = x;
    unsigned r = v.u + 0x7fffu + ((v.u >> 16) & 1u);
    return (unsigned short)(r >> 16);
}

// async global->LDS, 16B per lane. lds must be wave-uniform; dest = lds + lane*16.
__device__ __forceinline__ void async16(void* lds, const void* g) {
    __builtin_amdgcn_global_load_lds(
        (const __attribute__((address_space(1))) unsigned int*)g,
        (__attribute__((address_space(3))) unsigned int*)lds, 16, 0, 0);
}

// ---------------------------------------------------------------------------
// fp32 -> bf16 straight convert (8 elems/thread, exact grid)
// ---------------------------------------------------------------------------
__global__ __launch_bounds__(256) void convert_bf16_kernel(
    const float* __restrict__ in, unsigned short* __restrict__ out)
{
    const int i = blockIdx.x * 256 + threadIdx.x;
    const float4 a = ((const float4*)in)[i * 2];
    const float4 b = ((const float4*)in)[i * 2 + 1];
    union { unsigned short t[8]; uint4 u; } p;
    p.t[0] = f2bf(a.x); p.t[1] = f2bf(a.y); p.t[2] = f2bf(a.z); p.t[3] = f2bf(a.w);
    p.t[4] = f2bf(b.x); p.t[5] = f2bf(b.y); p.t[6] = f2bf(b.z); p.t[7] = f2bf(b.w);
    ((uint4*)out)[i] = p.u;
}

// ---------------------------------------------------------------------------
// fp32 [R][C] -> bf16 [C][R] tiled transpose-convert (64x64 tiles; R,C %64==0)
// ---------------------------------------------------------------------------
__global__ __launch_bounds__(256) void transpose_bf16_kernel(
    const float* __restrict__ in, unsigned short* __restrict__ out, int R, int C)
{
    __shared__ float T[64][65];
    const int tid = threadIdx.x;
    const int c0 = blockIdx.x * 64, r0 = blockIdx.y * 64;
    const int rl = tid >> 4, cl = (tid & 15) * 4;
#pragma unroll
    for (int i = 0; i < 4; ++i) {
        const int row = r0 + rl + i * 16;
        float4 v = *(const float4*)&in[(size_t)row * C + c0 + cl];
        T[cl + 0][rl + i * 16] = v.x; T[cl + 1][rl + i * 16] = v.y;
        T[cl + 2][rl + i * 16] = v.z; T[cl + 3][rl + i * 16] = v.w;
    }
    __syncthreads();
    const int oc = tid >> 2, ob = (tid & 3) * 16;
    union { unsigned short t[16]; uint4 u[2]; } p;
#pragma unroll
    for (int j = 0; j < 16; ++j) p.t[j] = f2bf(T[oc][ob + j]);
    uint4* dst = (uint4*)&out[(size_t)(c0 + oc) * R + r0 + ob];
    dst[0] = p.u[0];
    dst[1] = p.u[1];
}

// ---------------------------------------------------------------------------
// bf16 MFMA GEMM (m97 structure): C[M,N] = A[M,K] @ Bt[N,K]^T + bias, C fp32.
// 128x128 tile, BK=32, 256 thr = 4 waves (2x2 of 64x64), global_load_lds x16.
// ---------------------------------------------------------------------------
__global__ __launch_bounds__(256, 2) void gemm_bt_kernel(
    const unsigned short* __restrict__ A, const unsigned short* __restrict__ Bt,
    const float* __restrict__ bias, float* __restrict__ C, int M, int N, int K)
{
    __shared__ short As[128 * 32]; // [row][k] bf16, 8KB
    __shared__ short Bs[128 * 32];

    const int tid = threadIdx.x;
    const int w = tid >> 6, l = tid & 63;
    const int m0 = blockIdx.y * 128, n0 = blockIdx.x * 128;
    const int wr = w >> 1, wc = w & 1;
    const int lhi = l >> 4, llo = l & 15;

    f32x4 acc[4][4];
#pragma unroll
    for (int i = 0; i < 4; ++i)
#pragma unroll
        for (int j = 0; j < 4; ++j) acc[i][j] = f32x4{0.f, 0.f, 0.f, 0.f};

    // staging: chunk c = (w*2+s)*64 + l; row=c>>2, kg=(c&3)*8
    const int c0i = (w * 2) * 64 + l, c1i = c0i + 64;
    const unsigned short* gA0 = A + (size_t)min(m0 + (c0i >> 2), M - 1) * K + (c0i & 3) * 8;
    const unsigned short* gA1 = A + (size_t)min(m0 + (c1i >> 2), M - 1) * K + (c1i & 3) * 8;
    const unsigned short* gB0 = Bt + (size_t)(n0 + (c0i >> 2)) * K + (c0i & 3) * 8;
    const unsigned short* gB1 = Bt + (size_t)(n0 + (c1i >> 2)) * K + (c1i & 3) * 8;
    short* lA0 = As + (w * 2 + 0) * 512;
    short* lA1 = As + (w * 2 + 1) * 512;
    short* lB0 = Bs + (w * 2 + 0) * 512;
    short* lB1 = Bs + (w * 2 + 1) * 512;

    const int aoff = (wr * 64 + llo) * 32 + lhi * 8; // + mt*512
    const int boff = (wc * 64 + llo) * 32 + lhi * 8; // + nt*512

    for (int k0 = 0; k0 < K; k0 += 32) {
        async16(lA0, gA0 + k0); async16(lA1, gA1 + k0);
        async16(lB0, gB0 + k0); async16(lB1, gB1 + k0);
        __syncthreads();
        short8 af[4], bf[4];
#pragma unroll
        for (int mt = 0; mt < 4; ++mt) af[mt] = *(const short8*)&As[aoff + mt * 512];
#pragma unroll
        for (int nt = 0; nt < 4; ++nt) bf[nt] = *(const short8*)&Bs[boff + nt * 512];
#pragma unroll
        for (int mt = 0; mt < 4; ++mt)
#pragma unroll
            for (int nt = 0; nt < 4; ++nt)
                acc[mt][nt] = __builtin_amdgcn_mfma_f32_16x16x32_bf16(af[mt], bf[nt], acc[mt][nt], 0, 0, 0);
        __syncthreads();
    }

#pragma unroll
    for (int mt = 0; mt < 4; ++mt)
#pragma unroll
        for (int ri = 0; ri < 4; ++ri) {
            const int row = m0 + wr * 64 + mt * 16 + lhi * 4 + ri;
            if (row < M) {
#pragma unroll
                for (int nt = 0; nt < 4; ++nt) {
                    const int col = n0 + wc * 64 + nt * 16 + llo;
                    C[(size_t)row * N + col] = acc[mt][nt][ri] + bias[col];
                }
            }
        }
}

// ---------------------------------------------------------------------------
// RMSNorm(q,k over DIM) + RoPE + bf16 quantize; q pre-scaled by 1/sqrt(hd).
// One block per seq position.
// ---------------------------------------------------------------------------
__global__ __launch_bounds__(256) void rmsrope_kernel(
    const float* __restrict__ qkv, const float* __restrict__ gq,
    const float* __restrict__ gk, const float* __restrict__ cosf,
    const float* __restrict__ sinf, unsigned short* __restrict__ qb,
    unsigned short* __restrict__ kb)
{
    const int s = blockIdx.x;
    const int tid = threadIdx.x;
    const float* qrow = qkv + (size_t)s * QKV_N;
    const float* krow = qrow + DIM;

    float2 qp[3], kp[3];
    float ssq_q = 0.f, ssq_k = 0.f;
#pragma unroll
    for (int j = 0; j < 3; ++j) {
        const int p = tid + j * 256;
        qp[j] = *(const float2*)(qrow + 2 * p);
        kp[j] = *(const float2*)(krow + 2 * p);
        ssq_q += qp[j].x * qp[j].x + qp[j].y * qp[j].y;
        ssq_k += kp[j].x * kp[j].x + kp[j].y * kp[j].y;
    }
#pragma unroll
    for (int off = 32; off > 0; off >>= 1) {
        ssq_q += __shfl_down(ssq_q, off);
        ssq_k += __shfl_down(ssq_k, off);
    }
    __shared__ float wq[4], wk[4];
    const int wave = tid >> 6, lane = tid & 63;
    if (lane == 0) { wq[wave] = ssq_q; wk[wave] = ssq_k; }
    __syncthreads();
    const float tq = wq[0] + wq[1] + wq[2] + wq[3];
    const float tk = wk[0] + wk[1] + wk[2] + wk[3];
    const float inv_q = rsqrtf(tq * (1.0f / DIM) + 1e-6f) * SM_SCALE;
    const float inv_k = rsqrtf(tk * (1.0f / DIM) + 1e-6f);

#pragma unroll
    for (int j = 0; j < 3; ++j) {
        const int p = tid + j * 256;
        const int fi = p & 63;
        const float c = cosf[s * 64 + fi];
        const float si = sinf[s * 64 + fi];
        {
            const float y1 = qp[j].x * inv_q * gq[2 * p];
            const float y2 = qp[j].y * inv_q * gq[2 * p + 1];
            union { unsigned short t[2]; unsigned u; } o;
            o.t[0] = f2bf(y1 * c - y2 * si);
            o.t[1] = f2bf(y1 * si + y2 * c);
            *(unsigned*)&qb[(size_t)s * DIM + 2 * p] = o.u;
        }
        {
            const float y1 = kp[j].x * inv_k * gk[2 * p];
            const float y2 = kp[j].y * inv_k * gk[2 * p + 1];
            union { unsigned short t[2]; unsigned u; } o;
            o.t[0] = f2bf(y1 * c - y2 * si);
            o.t[1] = f2bf(y1 * si + y2 * c);
            *(unsigned*)&kb[(size_t)s * DIM + 2 * p] = o.u;
        }
    }
}

// ---------------------------------------------------------------------------
// V transpose: qkv v-part fp32 [s][h*128+d] -> vt bf16 [h][d][s]
// block = (64 seq rows, 1 head)
// ---------------------------------------------------------------------------
__global__ __launch_bounds__(256) void vtrans_kernel(
    const float* __restrict__ qkv, unsigned short* __restrict__ vt)
{
    __shared__ float T[128][65];
    const int s0 = blockIdx.x * 64;
    const int h = blockIdx.y;
    const int tid = threadIdx.x;
    const int rl = tid >> 2, cb = (tid & 3) * 32;
    const int row = min(s0 + rl, SEQ_LEN - 1);
#pragma unroll
    for (int i = 0; i < 8; ++i) {
        const int d = cb + i * 4;
        float4 v = *(const float4*)&qkv[(size_t)row * QKV_N + 2 * DIM + h * HEAD_DIM + d];
        T[d + 0][rl] = v.x; T[d + 1][rl] = v.y; T[d + 2][rl] = v.z; T[d + 3][rl] = v.w;
    }
    __syncthreads();
    const int od = tid >> 1, ob = (tid & 1) * 32;
    const size_t orow = (size_t)(h * HEAD_DIM + od) * SEQ_LEN;
#pragma unroll
    for (int j = 0; j < 32; ++j) {
        const int s = s0 + ob + j;
        if (s < SEQ_LEN) vt[orow + s] = f2bf(T[od][ob + j]);
    }
}

// ---------------------------------------------------------------------------
// Flash attention, bf16 MFMA. BQ=64 (4 waves x 16 rows), BK=64.
// Q,K staged [row][128]; V staged transposed [d][key] from pre-transposed vt.
// Softmax fp32 in registers (C-layout row groups); P via per-wave LDS strip.
// Output written bf16 (feeds the final GEMM directly).
// ---------------------------------------------------------------------------
__global__ __launch_bounds__(256, 2) void attn_mfma_kernel(
    const unsigned short* __restrict__ qb, const unsigned short* __restrict__ kb,
    const unsigned short* __restrict__ vt, unsigned short* __restrict__ attb)
{
    __shared__ short Qs[64 * 128];   // 16KB
    __shared__ short Ks[64 * 128];   // 16KB
    __shared__ short Vs[128 * 64];   // 16KB  [d][key]
    __shared__ short Ps[4 * 16 * 80]; // 10KB  per-wave [16 q][80] strip

    const int tid = threadIdx.x;
    const int w = tid >> 6, l = tid & 63;
    const int h = blockIdx.y;
    const int q0 = blockIdx.x * 64;
    const int lhi = l >> 4, llo = l & 15;

    // ---- stage Q (4 shots/wave) ----
#pragma unroll
    for (int s = 0; s < 4; ++s) {
        const int c = (w * 4 + s) * 64 + l;
        const int row = c >> 4, cg = c & 15;
        const int gr = min(q0 + row, SEQ_LEN - 1);
        async16(Qs + (w * 4 + s) * 512, qb + (size_t)gr * DIM + h * HEAD_DIM + cg * 8);
    }

    f32x4 o[8];
#pragma unroll
    for (int dt = 0; dt < 8; ++dt) o[dt] = f32x4{0.f, 0.f, 0.f, 0.f};
    float m_run[4], l_run[4];
#pragma unroll
    for (int ri = 0; ri < 4; ++ri) { m_run[ri] = -3.0e38f; l_run[ri] = 0.f; }

    const int qrow_base = q0 + w * 16 + lhi * 4;
    const int wave_min_limit = (q0 + w * 16 < FRAME_LEN) ? FRAME_LEN : SEQ_LEN;
    const int Lmax = (q0 + 64 > FRAME_LEN) ? SEQ_LEN : FRAME_LEN;

    short* Psw = Ps + w * 16 * 80;
    const int aoffQ = (w * 16 + llo) * 128 + lhi * 8;

    for (int kc = 0; kc < Lmax; kc += 64) {
        // ---- stage K [row][128] ----
#pragma unroll
        for (int s = 0; s < 4; ++s) {
            const int c = (w * 4 + s) * 64 + l;
            const int row = c >> 4, cg = c & 15;
            const int gr = min(kc + row, SEQ_LEN - 1);
            async16(Ks + (w * 4 + s) * 512, kb + (size_t)gr * DIM + h * HEAD_DIM + cg * 8);
        }
        // ---- stage V^T [d][key] ----
#pragma unroll
        for (int s = 0; s < 4; ++s) {
            const int c = (w * 4 + s) * 64 + l;
            const int d = c >> 3, cg = c & 7;
            int gk = kc + cg * 8;
            if (gk > SEQ_LEN - 8) gk = SEQ_LEN - 8;
            async16(Vs + (w * 4 + s) * 512, vt + (size_t)(h * HEAD_DIM + d) * SEQ_LEN + gk);
        }
        __syncthreads();

        // ---- S = Q K^T : wave strip 16 x 64 ----
        f32x4 sacc[4];
#pragma unroll
        for (int nt = 0; nt < 4; ++nt) sacc[nt] = f32x4{0.f, 0.f, 0.f, 0.f};
#pragma unroll
        for (int kd = 0; kd < 4; ++kd) {
            short8 aq = *(const short8*)&Qs[aoffQ + kd * 32];
#pragma unroll
            for (int nt = 0; nt < 4; ++nt) {
                short8 bk = *(const short8*)&Ks[(nt * 16 + llo) * 128 + kd * 32 + lhi * 8];
                sacc[nt] = __builtin_amdgcn_mfma_f32_16x16x32_bf16(aq, bk, sacc[nt], 0, 0, 0);
            }
        }

        // ---- block-causal mask (only near/after the frame boundary) ----
        if (kc + 64 > wave_min_limit) {
#pragma unroll
            for (int nt = 0; nt < 4; ++nt) {
                const int kg = kc + nt * 16 + llo;
#pragma unroll
                for (int ri = 0; ri < 4; ++ri) {
                    const int limit = (qrow_base + ri < FRAME_LEN) ? FRAME_LEN : SEQ_LEN;
                    if (kg >= limit) sacc[nt][ri] = -3.0e38f;
                }
            }
        }

        // ---- online softmax (row stats across llo lanes) ----
        float alpha[4];
#pragma unroll
        for (int ri = 0; ri < 4; ++ri) {
            float vmax = fmaxf(fmaxf(sacc[0][ri], sacc[1][ri]),
                               fmaxf(sacc[2][ri], sacc[3][ri]));
            vmax = fmaxf(vmax, __shfl_xor(vmax, 1));
            vmax = fmaxf(vmax, __shfl_xor(vmax, 2));
            vmax = fmaxf(vmax, __shfl_xor(vmax, 4));
            vmax = fmaxf(vmax, __shfl_xor(vmax, 8));
            const float mn = fmaxf(m_run[ri], vmax);
            alpha[ri] = __expf(m_run[ri] - mn);
            m_run[ri] = mn;
            float rs = 0.f;
#pragma unroll
            for (int nt = 0; nt < 4; ++nt) {
                const float p = __expf(sacc[nt][ri] - mn);
                sacc[nt][ri] = p;
                rs += p;
            }
            rs += __shfl_xor(rs, 1); rs += __shfl_xor(rs, 2);
            rs += __shfl_xor(rs, 4); rs += __shfl_xor(rs, 8);
            l_run[ri] = l_run[ri] * alpha[ri] + rs;
        }

        // ---- P -> LDS strip (bf16, A-layout source) ----
#pragma unroll
        for (int nt = 0; nt < 4; ++nt)
#pragma unroll
            for (int ri = 0; ri < 4; ++ri)
                Psw[(lhi * 4 + ri) * 80 + nt * 16 + llo] = (short)f2bf(sacc[nt][ri]);

        // ---- rescale O ----
#pragma unroll
        for (int dt = 0; dt < 8; ++dt)
#pragma unroll
            for (int ri = 0; ri < 4; ++ri) o[dt][ri] *= alpha[ri];

        // ---- O += P V ----
#pragma unroll
        for (int ks = 0; ks < 2; ++ks) {
            short8 ap = *(const short8*)&Psw[llo * 80 + ks * 32 + lhi * 8];
#pragma unroll
            for (int dt = 0; dt < 8; ++dt) {
                short8 bv = *(const short8*)&Vs[(dt * 16 + llo) * 64 + ks * 32 + lhi * 8];
                o[dt] = __builtin_amdgcn_mfma_f32_16x16x32_bf16(ap, bv, o[dt], 0, 0, 0);
            }
        }
        __syncthreads(); // protect Ks/Vs before restage
    }

    // ---- epilogue: O /= l, store bf16 [s][h*128+d] ----
#pragma unroll
    for (int ri = 0; ri < 4; ++ri) {
        const int sg = qrow_base + ri;
        if (sg < SEQ_LEN) {
            const float inv = 1.0f / l_run[ri];
#pragma unroll
            for (int dt = 0; dt < 8; ++dt)
                attb[(size_t)sg * DIM + h * HEAD_DIM + dt * 16 + llo] =
                    f2bf(o[dt][ri] * inv);
        }
    }
}

// ---------------------------------------------------------------------------
extern "C" void kernel_launch(void* const* d_in, const int* in_sizes, int n_in,
                              void* d_out, int out_size, void* d_ws, size_t ws_size,
                              hipStream_t stream)
{
    const float* hs    = (const float*)d_in[0];
    const float* cosf  = (const float*)d_in[1];
    const float* sinf  = (const float*)d_in[2];
    const float* w_qkv = (const float*)d_in[3];
    const float* b_qkv = (const float*)d_in[4];
    const float* g_q   = (const float*)d_in[5];
    const float* g_k   = (const float*)d_in[6];
    const float* w_out = (const float*)d_in[7];
    const float* b_out = (const float*)d_in[8];

    // workspace layout (105.1 MB total)
    char* base = (char*)d_ws;
    float* qkv           = (float*)base;                       // 57,507,840 B fp32 [3120][4608]
    char* bufB = base + 57507840;  // 9,584,640 B : hsb, later vt
    char* bufC = bufB + 9584640;   // 14,155,776 B: wqkvT, later attb
    char* bufD = bufC + 14155776;  // 4,718,592 B : woutT
    char* bufE = bufD + 4718592;   // 9,584,640 B : qb
    char* bufF = bufE + 9584640;   // 9,584,640 B : kb
    unsigned short* hsb   = (unsigned short*)bufB;
    unsigned short* vt    = (unsigned short*)bufB;
    unsigned short* wqkvT = (unsigned short*)bufC;
    unsigned short* attb  = (unsigned short*)bufC;
    unsigned short* woutT = (unsigned short*)bufD;
    unsigned short* qb    = (unsigned short*)bufE;
    unsigned short* kb    = (unsigned short*)bufF;
    float* outp = (float*)d_out;

    // 1) convert hs -> bf16 (3120*1536/8/256 = 2340 blocks, exact)
    convert_bf16_kernel<<<2340, 256, 0, stream>>>(hs, hsb);
    // 2) w_qkv [1536][4608] -> wqkvT bf16 [4608][1536]
    transpose_bf16_kernel<<<dim3(QKV_N / 64, DIM / 64), 256, 0, stream>>>(w_qkv, wqkvT, DIM, QKV_N);
    // 3) w_out [1536][1536] -> woutT bf16 [1536][1536]
    transpose_bf16_kernel<<<dim3(DIM / 64, DIM / 64), 256, 0, stream>>>(w_out, woutT, DIM, DIM);
    // 4) qkv = hs @ w_qkv + b_qkv   (fp32 out)
    gemm_bt_kernel<<<dim3(QKV_N / 128, (SEQ_LEN + 127) / 128), 256, 0, stream>>>(
        hsb, wqkvT, b_qkv, qkv, SEQ_LEN, QKV_N, DIM);
    // 5) rmsnorm+rope -> qb, kb (bf16; q pre-scaled)
    rmsrope_kernel<<<SEQ_LEN, 256, 0, stream>>>(qkv, g_q, g_k, cosf, sinf, qb, kb);
    // 6) v -> vt bf16 [h][d][s]
    vtrans_kernel<<<dim3((SEQ_LEN + 63) / 64, HEADS), 256, 0, stream>>>(qkv, vt);
    // 7) attention -> attb bf16 [s][h*128+d]
    attn_mfma_kernel<<<dim3((SEQ_LEN + 63) / 64, HEADS), 256, 0, stream>>>(qb, kb, vt, attb);
    // 8) out = attb @ w_out + b_out (fp32)
    gemm_bt_kernel<<<dim3(DIM / 128, (SEQ_LEN + 127) / 128), 256, 0, stream>>>(
        attb, woutT, b_out, outp, SEQ_LEN, DIM, DIM);
}